// Round 1
// baseline (16851.003 us; speedup 1.0000x reference)
//
#include <hip/hip_runtime.h>
#include <math.h>

#define B_  32
#define S_  512
#define H_  1024
#define G3_ 3072

typedef __attribute__((ext_vector_type(8))) short bf16x8;   // 8 bf16 in 4 VGPRs
typedef __attribute__((ext_vector_type(4))) float f32x4;

__device__ __forceinline__ unsigned short f2bf(float f) {
  unsigned int u = __float_as_uint(f);
  u = (u + 0x7FFFu + ((u >> 16) & 1u)) >> 16;   // RNE
  return (unsigned short)u;
}
__device__ __forceinline__ float bf2f(unsigned short h) {
  return __uint_as_float(((unsigned int)h) << 16);
}

__global__ void cast_f32_bf16(const float* __restrict__ in, unsigned short* __restrict__ out, int n) {
  int i = blockIdx.x * 256 + threadIdx.x;
  if (i < n) out[i] = f2bf(in[i]);
}

// C[m,n] = sum_k A[m,k]*W[n,k] + bias[n]
// A bf16 (M x K) with optional row permutation m -> (m&31)*S_ + (m>>5)  (time-major <-> batch-major)
// W bf16 (N x K), C rows optionally permuted the same way. CT = float or ushort(bf16).
template<int APERM, int CPERM, typename CT>
__global__ __launch_bounds__(256)
void gemm_bf16(const unsigned short* __restrict__ A, const unsigned short* __restrict__ W,
               const float* __restrict__ bias, CT* __restrict__ C, int M, int N, int K) {
  __shared__ __align__(16) unsigned short As[128 * 40];  // [row][k] pad to 40 elems (80B) -> 2-way max bank aliasing
  __shared__ __align__(16) unsigned short Ws[128 * 40];
  const int tid   = threadIdx.x;
  const int mBase = blockIdx.y * 128;
  const int nBase = blockIdx.x * 128;
  const int lane  = tid & 63;
  const int w     = tid >> 6;
  const int wm    = (w & 1) * 64;
  const int wn    = (w >> 1) * 64;
  const int r16   = lane & 15;
  const int q     = lane >> 4;

  f32x4 acc[4][4];
  for (int i = 0; i < 4; ++i)
    for (int j = 0; j < 4; ++j)
      for (int t = 0; t < 4; ++t) acc[i][j][t] = 0.f;

  const int r0  = tid >> 2;          // 0..63
  const int kk0 = (tid & 3) * 8;     // 0,8,16,24

  for (int k0 = 0; k0 < K; k0 += 32) {
    {
      int r = r0;
      size_t ar = APERM ? ((size_t)((mBase + r) & 31) * S_ + (size_t)((mBase + r) >> 5)) : (size_t)(mBase + r);
      *(uint4*)&As[r * 40 + kk0] = *(const uint4*)(A + ar * K + k0 + kk0);
      int r2 = r + 64;
      size_t ar2 = APERM ? ((size_t)((mBase + r2) & 31) * S_ + (size_t)((mBase + r2) >> 5)) : (size_t)(mBase + r2);
      *(uint4*)&As[r2 * 40 + kk0] = *(const uint4*)(A + ar2 * K + k0 + kk0);
      *(uint4*)&Ws[r * 40 + kk0]  = *(const uint4*)(W + (size_t)(nBase + r)  * K + k0 + kk0);
      *(uint4*)&Ws[r2 * 40 + kk0] = *(const uint4*)(W + (size_t)(nBase + r2) * K + k0 + kk0);
    }
    __syncthreads();
    bf16x8 af[4], bfr[4];
#pragma unroll
    for (int i = 0; i < 4; ++i) af[i]  = *(const bf16x8*)&As[(wm + i * 16 + r16) * 40 + q * 8];
#pragma unroll
    for (int j = 0; j < 4; ++j) bfr[j] = *(const bf16x8*)&Ws[(wn + j * 16 + r16) * 40 + q * 8];
#pragma unroll
    for (int i = 0; i < 4; ++i)
#pragma unroll
      for (int j = 0; j < 4; ++j)
        acc[i][j] = __builtin_amdgcn_mfma_f32_16x16x32_bf16(af[i], bfr[j], acc[i][j], 0, 0, 0);
    __syncthreads();
  }

  // C/D layout: n = lane&15, m = (lane>>4)*4 + reg  [verified mapping]
#pragma unroll
  for (int i = 0; i < 4; ++i)
#pragma unroll
    for (int j = 0; j < 4; ++j)
#pragma unroll
      for (int t = 0; t < 4; ++t) {
        int m = mBase + wm + i * 16 + q * 4 + t;
        int n = nBase + wn + j * 16 + r16;
        float v = acc[i][j][t] + bias[n];
        size_t crow = CPERM ? ((size_t)(m & 31) * S_ + (size_t)(m >> 5)) : (size_t)m;
        if constexpr (sizeof(CT) == 4) C[crow * N + n] = v;
        else                           C[crow * N + n] = f2bf(v);
      }
}

// One GRU timestep: gates = h_prev @ Whh^T (bf16 MFMA), then pointwise.
// Block: 3 waves (192 thr); wave g computes gate g for j in [j0, j0+16).
template<typename XPT>
__global__ __launch_bounds__(192)
void gru_step(const unsigned short* __restrict__ Whh, const XPT* __restrict__ xp_t,
              const unsigned short* __restrict__ hprev_b, const float* __restrict__ hprev_f,
              unsigned short* __restrict__ y_t, float* __restrict__ hout) {
  __shared__ __align__(16) unsigned short hs[32 * 40];
  __shared__ __align__(16) unsigned short ws[48 * 40];
  __shared__ float gx[3][32][16];
  const int tid  = threadIdx.x;
  const int j0   = blockIdx.x * 16;
  const int lane = tid & 63;
  const int g    = tid >> 6;     // wave id == gate id (0=r,1=z,2=n)
  const int r16  = lane & 15;
  const int q    = lane >> 4;

  f32x4 acc[2];
  for (int t = 0; t < 4; ++t) { acc[0][t] = 0.f; acc[1][t] = 0.f; }

  const int rs = tid >> 2;          // W rows 0..47
  const int kk = (tid & 3) * 8;
  const int gg = rs >> 4, jj = rs & 15;

  for (int k0 = 0; k0 < H_; k0 += 32) {
    if (tid < 128) {                // stage h: 32 rows x 32 k
      *(uint4*)&hs[rs * 40 + kk] = *(const uint4*)(hprev_b + (size_t)rs * H_ + k0 + kk);
    }
    // stage W: 48 rows (3 gates x 16 j) x 32 k
    *(uint4*)&ws[rs * 40 + kk] = *(const uint4*)(Whh + (size_t)(gg * H_ + j0 + jj) * H_ + k0 + kk);
    __syncthreads();
    bf16x8 bfr = *(const bf16x8*)&ws[(g * 16 + r16) * 40 + q * 8];
#pragma unroll
    for (int i = 0; i < 2; ++i) {
      bf16x8 af = *(const bf16x8*)&hs[(i * 16 + r16) * 40 + q * 8];
      acc[i] = __builtin_amdgcn_mfma_f32_16x16x32_bf16(af, bfr, acc[i], 0, 0, 0);
    }
    __syncthreads();
  }

#pragma unroll
  for (int i = 0; i < 2; ++i)
#pragma unroll
    for (int t = 0; t < 4; ++t)
      gx[g][i * 16 + q * 4 + t][r16] = acc[i][t];   // [gate][batch][j]
  __syncthreads();

  if (tid < 128) {
#pragma unroll
    for (int u = 0; u < 4; ++u) {
      int o = tid + u * 128;         // 512 outputs = 32 b x 16 j
      int b = o >> 4, j = o & 15;
      int jg = j0 + j;
      float xr, xz, xn;
      if constexpr (sizeof(XPT) == 4) {
        xr = xp_t[b * G3_ + jg]; xz = xp_t[b * G3_ + H_ + jg]; xn = xp_t[b * G3_ + 2 * H_ + jg];
      } else {
        xr = bf2f(xp_t[b * G3_ + jg]); xz = bf2f(xp_t[b * G3_ + H_ + jg]); xn = bf2f(xp_t[b * G3_ + 2 * H_ + jg]);
      }
      float hr = gx[0][b][j], hz = gx[1][b][j], hn = gx[2][b][j];
      float r = 1.f / (1.f + expf(-(xr + hr)));
      float z = 1.f / (1.f + expf(-(xz + hz)));
      float nn = tanhf(xn + hn + r * hn);          // ref: tanh(n_gate + r*(h@Whn^T))
      float hp = hprev_f[b * H_ + jg];
      float hv = (1.f - z) * nn + z * hp;
      y_t[b * H_ + jg]  = f2bf(hv);
      hout[b * H_ + jg] = hv;
    }
  }
}

extern "C" void kernel_launch(void* const* d_in, const int* in_sizes, int n_in,
                              void* d_out, int out_size, void* d_ws, size_t ws_size,
                              hipStream_t stream) {
  const float* x    = (const float*)d_in[0];
  const float* Wih0 = (const float*)d_in[1];
  const float* Whh0 = (const float*)d_in[2];
  const float* b0   = (const float*)d_in[3];
  const float* Wih1 = (const float*)d_in[4];
  const float* Whh1 = (const float*)d_in[5];
  const float* b1   = (const float*)d_in[6];
  const float* Wlin = (const float*)d_in[7];
  const float* blin = (const float*)d_in[8];
  float* out = (float*)d_out;

  // workspace layout (deterministic per call; xp precision chosen by ws_size)
  const bool xpf32 = ws_size >= (size_t)308740096;
  char* p = (char*)d_ws;
  size_t off = 0;
  auto alloc = [&](size_t bytes) { void* r = p + off; off += (bytes + 255) & ~(size_t)255; return r; };

  void* xp = alloc(xpf32 ? (size_t)16384 * G3_ * 4 : (size_t)16384 * G3_ * 2);
  unsigned short* xb    = (unsigned short*)alloc((size_t)8388608 * 2);
  unsigned short* wih0b = (unsigned short*)alloc((size_t)1572864 * 2);
  unsigned short* whh0b = (unsigned short*)alloc((size_t)3145728 * 2);
  unsigned short* wih1b = (unsigned short*)alloc((size_t)3145728 * 2);
  unsigned short* whh1b = (unsigned short*)alloc((size_t)3145728 * 2);
  unsigned short* wlinb = (unsigned short*)alloc((size_t)524288 * 2);
  unsigned short* y0b   = (unsigned short*)alloc((size_t)16777216 * 2);  // (S,B,H) time-major bf16
  unsigned short* y1b   = (unsigned short*)alloc((size_t)16777216 * 2);
  float* hbuf           = (float*)alloc((size_t)2 * B_ * H_ * 4);        // fp32 h ping-pong
  float* zerosF         = (float*)alloc((size_t)B_ * H_ * 4);
  unsigned short* zerosB= (unsigned short*)alloc((size_t)B_ * H_ * 2);

  hipMemsetAsync(zerosF, 0, (size_t)B_ * H_ * 4, stream);
  hipMemsetAsync(zerosB, 0, (size_t)B_ * H_ * 2, stream);

  auto cast = [&](const float* in, unsigned short* o, int n) {
    cast_f32_bf16<<<n / 256, 256, 0, stream>>>(in, o, n);
  };
  cast(x, xb, 8388608);
  cast(Wih0, wih0b, 1572864);
  cast(Whh0, whh0b, 3145728);
  cast(Wih1, wih1b, 3145728);
  cast(Whh1, whh1b, 3145728);
  cast(Wlin, wlinb, 524288);

  auto run_layer = [&](const unsigned short* whhb, void* xpPtr, unsigned short* yb) {
    for (int t = 0; t < S_; ++t) {
      const unsigned short* hp_b = t ? yb + (size_t)(t - 1) * (B_ * H_) : zerosB;
      const float* hp_f = t ? hbuf + ((t - 1) & 1) * (B_ * H_) : zerosF;
      unsigned short* yt = yb + (size_t)t * (B_ * H_);
      float* ho = hbuf + (t & 1) * (B_ * H_);
      if (xpf32)
        gru_step<float><<<64, 192, 0, stream>>>(whhb, (const float*)xpPtr + (size_t)t * (B_ * G3_), hp_b, hp_f, yt, ho);
      else
        gru_step<unsigned short><<<64, 192, 0, stream>>>(whhb, (const unsigned short*)xpPtr + (size_t)t * (B_ * G3_), hp_b, hp_f, yt, ho);
    }
  };

  // xproj0: (16384 x 3072 x 512), A = x (batch-major -> APERM), C = xp (time-major)
  {
    dim3 g(G3_ / 128, 16384 / 128);
    if (xpf32) gemm_bf16<1, 0, float><<<g, 256, 0, stream>>>(xb, wih0b, b0, (float*)xp, 16384, G3_, 512);
    else       gemm_bf16<1, 0, unsigned short><<<g, 256, 0, stream>>>(xb, wih0b, b0, (unsigned short*)xp, 16384, G3_, 512);
  }
  run_layer(whh0b, xp, y0b);
  // h_last0 (fp32, step 511 -> ping-pong slot 1)
  hipMemcpyAsync(out + 8388608, hbuf + B_ * H_, (size_t)B_ * H_ * 4, hipMemcpyDeviceToDevice, stream);

  // xproj1: (16384 x 3072 x 1024), A = y0b time-major (no perm)
  {
    dim3 g(G3_ / 128, 16384 / 128);
    if (xpf32) gemm_bf16<0, 0, float><<<g, 256, 0, stream>>>(y0b, wih1b, b1, (float*)xp, 16384, G3_, 1024);
    else       gemm_bf16<0, 0, unsigned short><<<g, 256, 0, stream>>>(y0b, wih1b, b1, (unsigned short*)xp, 16384, G3_, 1024);
  }
  run_layer(whh1b, xp, y1b);
  hipMemcpyAsync(out + 8388608 + B_ * H_, hbuf + B_ * H_, (size_t)B_ * H_ * 4, hipMemcpyDeviceToDevice, stream);

  // final: out = y1 @ Wlin^T + blin, (16384 x 512 x 1024), C rows permuted to (b,s)
  {
    dim3 g(512 / 128, 16384 / 128);
    gemm_bf16<0, 1, float><<<g, 256, 0, stream>>>(y1b, wlinb, blin, out, 16384, 512, 1024);
  }
}

// Round 3
// 15870.370 us; speedup vs baseline: 1.0618x; 1.0618x over previous
//
#include <hip/hip_runtime.h>
#include <math.h>

#define B_  32
#define S_  512
#define H_  1024
#define G3_ 3072

typedef __attribute__((ext_vector_type(8))) short bf16x8;   // 8 bf16 in 4 VGPRs
typedef __attribute__((ext_vector_type(4))) float f32x4;

__device__ __forceinline__ unsigned short f2bf(float f) {
  unsigned int u = __float_as_uint(f);
  u = (u + 0x7FFFu + ((u >> 16) & 1u)) >> 16;   // RNE
  return (unsigned short)u;
}
__device__ __forceinline__ float bf2f(unsigned short h) {
  return __uint_as_float(((unsigned int)h) << 16);
}

__global__ void cast_f32_bf16(const float* __restrict__ in, unsigned short* __restrict__ out, int n) {
  int i = blockIdx.x * 256 + threadIdx.x;
  if (i < n) out[i] = f2bf(in[i]);
}

// ---------------- big GEMM (unchanged, verified in R1) ----------------
// C[m,n] = sum_k A[m,k]*W[n,k] + bias[n]
template<int APERM, int CPERM, typename CT>
__global__ __launch_bounds__(256)
void gemm_bf16(const unsigned short* __restrict__ A, const unsigned short* __restrict__ W,
               const float* __restrict__ bias, CT* __restrict__ C, int M, int N, int K) {
  __shared__ __align__(16) unsigned short As[128 * 40];
  __shared__ __align__(16) unsigned short Ws[128 * 40];
  const int tid   = threadIdx.x;
  const int mBase = blockIdx.y * 128;
  const int nBase = blockIdx.x * 128;
  const int lane  = tid & 63;
  const int w     = tid >> 6;
  const int wm    = (w & 1) * 64;
  const int wn    = (w >> 1) * 64;
  const int r16   = lane & 15;
  const int q     = lane >> 4;

  f32x4 acc[4][4];
  for (int i = 0; i < 4; ++i)
    for (int j = 0; j < 4; ++j)
      for (int t = 0; t < 4; ++t) acc[i][j][t] = 0.f;

  const int r0  = tid >> 2;
  const int kk0 = (tid & 3) * 8;

  for (int k0 = 0; k0 < K; k0 += 32) {
    {
      int r = r0;
      size_t ar = APERM ? ((size_t)((mBase + r) & 31) * S_ + (size_t)((mBase + r) >> 5)) : (size_t)(mBase + r);
      *(uint4*)&As[r * 40 + kk0] = *(const uint4*)(A + ar * K + k0 + kk0);
      int r2 = r + 64;
      size_t ar2 = APERM ? ((size_t)((mBase + r2) & 31) * S_ + (size_t)((mBase + r2) >> 5)) : (size_t)(mBase + r2);
      *(uint4*)&As[r2 * 40 + kk0] = *(const uint4*)(A + ar2 * K + k0 + kk0);
      *(uint4*)&Ws[r * 40 + kk0]  = *(const uint4*)(W + (size_t)(nBase + r)  * K + k0 + kk0);
      *(uint4*)&Ws[r2 * 40 + kk0] = *(const uint4*)(W + (size_t)(nBase + r2) * K + k0 + kk0);
    }
    __syncthreads();
    bf16x8 af[4], bfr[4];
#pragma unroll
    for (int i = 0; i < 4; ++i) af[i]  = *(const bf16x8*)&As[(wm + i * 16 + r16) * 40 + q * 8];
#pragma unroll
    for (int j = 0; j < 4; ++j) bfr[j] = *(const bf16x8*)&Ws[(wn + j * 16 + r16) * 40 + q * 8];
#pragma unroll
    for (int i = 0; i < 4; ++i)
#pragma unroll
      for (int j = 0; j < 4; ++j)
        acc[i][j] = __builtin_amdgcn_mfma_f32_16x16x32_bf16(af[i], bfr[j], acc[i][j], 0, 0, 0);
    __syncthreads();
  }

#pragma unroll
  for (int i = 0; i < 4; ++i)
#pragma unroll
    for (int j = 0; j < 4; ++j)
#pragma unroll
      for (int t = 0; t < 4; ++t) {
        int m = mBase + wm + i * 16 + q * 4 + t;
        int n = nBase + wn + j * 16 + r16;
        float v = acc[i][j][t] + bias[n];
        size_t crow = CPERM ? ((size_t)(m & 31) * S_ + (size_t)(m >> 5)) : (size_t)m;
        if constexpr (sizeof(CT) == 4) C[crow * N + n] = v;
        else                           C[crow * N + n] = f2bf(v);
      }
}

// ---------------- persistent GRU layer ----------------
// 64 blocks x 192 threads. Block b: j-slice [b*16, b*16+16). Wave g computes gate g.
// Whh slice staged ONCE into LDS in packed per-lane B-frag order.
// h A-frags read direct global->register. Grid barrier (striped counters) per step.

__device__ __forceinline__ void grid_barrier(unsigned int* ctrs, unsigned int target) {
  __threadfence();   // release: own y/h stores visible at agent scope before arrival
  __syncthreads();
  if (threadIdx.x == 0)
    __hip_atomic_fetch_add(&ctrs[(blockIdx.x & 7) * 16], 1u,
                           __ATOMIC_RELAXED, __HIP_MEMORY_SCOPE_AGENT);
  if (threadIdx.x < 64) {
    for (;;) {
      unsigned int v = (threadIdx.x < 8)
        ? __hip_atomic_load(&ctrs[threadIdx.x * 16], __ATOMIC_RELAXED, __HIP_MEMORY_SCOPE_AGENT)
        : 0u;
      v += __shfl_xor(v, 1);
      v += __shfl_xor(v, 2);
      v += __shfl_xor(v, 4);
      v = __shfl(v, 0);
      if (v >= target) break;
      __builtin_amdgcn_s_sleep(1);
    }
  }
  __syncthreads();
  __threadfence();   // acquire: don't let subsequent loads see stale caches
}

template<typename XPT>
__global__ __launch_bounds__(192)
void gru_layer(const unsigned short* __restrict__ Whh, const XPT* __restrict__ xp,
               const unsigned short* __restrict__ h0b, const float* __restrict__ h0f,
               unsigned short* __restrict__ y, float* __restrict__ hbuf,
               unsigned int* __restrict__ ctrs) {
  __shared__ __align__(16) unsigned short wpack[3 * 32 * 64 * 8];  // 96 KB
  __shared__ float gx[3][32][16];
  const int tid  = threadIdx.x;
  const int j0   = blockIdx.x * 16;
  const int lane = tid & 63;
  const int g    = tid >> 6;     // wave id == gate (0=r,1=z,2=n)
  const int r16  = lane & 15;
  const int q    = lane >> 4;

  // one-time: pack W gate-slices into per-lane frag order
  for (int f = tid; f < 6144; f += 192) {
    int l = f & 63, c = (f >> 6) & 31, gg = f >> 11;
    int row = l & 15, k = c * 32 + ((l >> 4) << 3);
    *(uint4*)&wpack[f * 8] = *(const uint4*)(Whh + (size_t)(gg * H_ + j0 + row) * H_ + k);
  }
  __syncthreads();

  for (int t = 0; t < S_; ++t) {
    const unsigned short* hp  = t ? y + (size_t)(t - 1) * (B_ * H_) : h0b;
    const float*          hpf = t ? hbuf + ((t - 1) & 1) * (B_ * H_) : h0f;
    const XPT*            xpt = xp + (size_t)t * (B_ * G3_);
    unsigned short*       yt  = y + (size_t)t * (B_ * H_);
    float*                ho  = hbuf + (t & 1) * (B_ * H_);

    // prefetch xp (launch-constant) and hpf (valid post-barrier) for epilogue
    float pxr[4], pxz[4], pxn[4], phv[4];
    if (tid < 128) {
#pragma unroll
      for (int u = 0; u < 4; ++u) {
        int o = tid + u * 128;
        int b = o >> 4, j = o & 15, jg = j0 + j;
        if constexpr (sizeof(XPT) == 4) {
          pxr[u] = xpt[b * G3_ + jg];
          pxz[u] = xpt[b * G3_ + H_ + jg];
          pxn[u] = xpt[b * G3_ + 2 * H_ + jg];
        } else {
          pxr[u] = bf2f(xpt[b * G3_ + jg]);
          pxz[u] = bf2f(xpt[b * G3_ + H_ + jg]);
          pxn[u] = bf2f(xpt[b * G3_ + 2 * H_ + jg]);
        }
        phv[u] = hpf[b * H_ + jg];
      }
    }

    f32x4 acc0, acc1;
#pragma unroll
    for (int u = 0; u < 4; ++u) { acc0[u] = 0.f; acc1[u] = 0.f; }

#pragma unroll 8
    for (int c = 0; c < 32; ++c) {
      bf16x8 bfr = *(const bf16x8*)&wpack[((g * 32 + c) * 64 + lane) * 8];
      bf16x8 a0  = *(const bf16x8*)(hp + (size_t)r16 * H_ + c * 32 + q * 8);
      bf16x8 a1  = *(const bf16x8*)(hp + (size_t)(16 + r16) * H_ + c * 32 + q * 8);
      acc0 = __builtin_amdgcn_mfma_f32_16x16x32_bf16(a0, bfr, acc0, 0, 0, 0);
      acc1 = __builtin_amdgcn_mfma_f32_16x16x32_bf16(a1, bfr, acc1, 0, 0, 0);
    }

#pragma unroll
    for (int u = 0; u < 4; ++u) {
      gx[g][q * 4 + u][r16]      = acc0[u];
      gx[g][16 + q * 4 + u][r16] = acc1[u];
    }
    __syncthreads();

    if (tid < 128) {
#pragma unroll
      for (int u = 0; u < 4; ++u) {
        int o = tid + u * 128;
        int b = o >> 4, j = o & 15, jg = j0 + j;
        float hr = gx[0][b][j], hz = gx[1][b][j], hn = gx[2][b][j];
        float r  = 1.f / (1.f + expf(-(pxr[u] + hr)));
        float z  = 1.f / (1.f + expf(-(pxz[u] + hz)));
        float nn = tanhf(pxn[u] + hn + r * hn);
        float hv = (1.f - z) * nn + z * phv[u];
        yt[b * H_ + jg] = f2bf(hv);
        ho[b * H_ + jg] = hv;
      }
    }

    grid_barrier(ctrs, (unsigned)(t + 1) * 64u);
  }
}

extern "C" void kernel_launch(void* const* d_in, const int* in_sizes, int n_in,
                              void* d_out, int out_size, void* d_ws, size_t ws_size,
                              hipStream_t stream) {
  const float* x    = (const float*)d_in[0];
  const float* Wih0 = (const float*)d_in[1];
  const float* Whh0 = (const float*)d_in[2];
  const float* b0   = (const float*)d_in[3];
  const float* Wih1 = (const float*)d_in[4];
  const float* Whh1 = (const float*)d_in[5];
  const float* b1   = (const float*)d_in[6];
  const float* Wlin = (const float*)d_in[7];
  const float* blin = (const float*)d_in[8];
  float* out = (float*)d_out;

  const bool xpf32 = ws_size >= (size_t)308741120;
  char* p = (char*)d_ws;
  size_t off = 0;
  auto alloc = [&](size_t bytes) { void* r = p + off; off += (bytes + 255) & ~(size_t)255; return r; };

  void* xp = alloc(xpf32 ? (size_t)16384 * G3_ * 4 : (size_t)16384 * G3_ * 2);
  unsigned short* xb    = (unsigned short*)alloc((size_t)8388608 * 2);
  unsigned short* wih0b = (unsigned short*)alloc((size_t)1572864 * 2);
  unsigned short* whh0b = (unsigned short*)alloc((size_t)3145728 * 2);
  unsigned short* wih1b = (unsigned short*)alloc((size_t)3145728 * 2);
  unsigned short* whh1b = (unsigned short*)alloc((size_t)3145728 * 2);
  unsigned short* wlinb = (unsigned short*)alloc((size_t)524288 * 2);
  unsigned short* y0b   = (unsigned short*)alloc((size_t)16777216 * 2);  // (S,B,H) bf16
  unsigned short* y1b   = (unsigned short*)alloc((size_t)16777216 * 2);
  float* hbuf           = (float*)alloc((size_t)2 * B_ * H_ * 4);
  float* zerosF         = (float*)alloc((size_t)B_ * H_ * 4);
  unsigned short* zerosB= (unsigned short*)alloc((size_t)B_ * H_ * 2);
  unsigned int* ctrs0   = (unsigned int*)alloc(512);
  unsigned int* ctrs1   = (unsigned int*)alloc(512);

  (void)hipMemsetAsync(zerosF, 0, (size_t)B_ * H_ * 4, stream);
  (void)hipMemsetAsync(zerosB, 0, (size_t)B_ * H_ * 2, stream);
  (void)hipMemsetAsync(ctrs0, 0, 512, stream);
  (void)hipMemsetAsync(ctrs1, 0, 512, stream);

  auto cast = [&](const float* in, unsigned short* o, int n) {
    cast_f32_bf16<<<n / 256, 256, 0, stream>>>(in, o, n);
  };
  cast(x, xb, 8388608);
  cast(Wih0, wih0b, 1572864);
  cast(Whh0, whh0b, 3145728);
  cast(Wih1, wih1b, 3145728);
  cast(Whh1, whh1b, 3145728);
  cast(Wlin, wlinb, 524288);

  // xproj0: (16384 x 3072 x 512), A = x batch-major (perm), C time-major
  {
    dim3 g(G3_ / 128, 16384 / 128);
    if (xpf32) gemm_bf16<1, 0, float><<<g, 256, 0, stream>>>(xb, wih0b, b0, (float*)xp, 16384, G3_, 512);
    else       gemm_bf16<1, 0, unsigned short><<<g, 256, 0, stream>>>(xb, wih0b, b0, (unsigned short*)xp, 16384, G3_, 512);
  }

  if (xpf32) gru_layer<float><<<64, 192, 0, stream>>>(whh0b, (const float*)xp, zerosB, zerosF, y0b, hbuf, ctrs0);
  else       gru_layer<unsigned short><<<64, 192, 0, stream>>>(whh0b, (const unsigned short*)xp, zerosB, zerosF, y0b, hbuf, ctrs0);
  (void)hipMemcpyAsync(out + 8388608, hbuf + B_ * H_, (size_t)B_ * H_ * 4, hipMemcpyDeviceToDevice, stream);

  // xproj1: (16384 x 3072 x 1024), A = y0b time-major
  {
    dim3 g(G3_ / 128, 16384 / 128);
    if (xpf32) gemm_bf16<0, 0, float><<<g, 256, 0, stream>>>(y0b, wih1b, b1, (float*)xp, 16384, G3_, 1024);
    else       gemm_bf16<0, 0, unsigned short><<<g, 256, 0, stream>>>(y0b, wih1b, b1, (unsigned short*)xp, 16384, G3_, 1024);
  }

  if (xpf32) gru_layer<float><<<64, 192, 0, stream>>>(whh1b, (const float*)xp, zerosB, zerosF, y1b, hbuf, ctrs1);
  else       gru_layer<unsigned short><<<64, 192, 0, stream>>>(whh1b, (const unsigned short*)xp, zerosB, zerosF, y1b, hbuf, ctrs1);
  (void)hipMemcpyAsync(out + 8388608 + B_ * H_, hbuf + B_ * H_, (size_t)B_ * H_ * 4, hipMemcpyDeviceToDevice, stream);

  // final: out = y1 @ Wlin^T + blin, C rows -> (b,s)
  {
    dim3 g(512 / 128, 16384 / 128);
    gemm_bf16<0, 1, float><<<g, 256, 0, stream>>>(y1b, wlinb, blin, out, 16384, 512, 1024);
  }
}

// Round 5
// 6563.913 us; speedup vs baseline: 2.5672x; 2.4178x over previous
//
#include <hip/hip_runtime.h>
#include <math.h>

#define B_  32
#define S_  512
#define H_  1024
#define G3_ 3072

typedef __attribute__((ext_vector_type(8))) short bf16x8;   // 8 bf16 in 4 VGPRs
typedef __attribute__((ext_vector_type(4))) float f32x4;

__device__ __forceinline__ unsigned short f2bf(float f) {
  unsigned int u = __float_as_uint(f);
  u = (u + 0x7FFFu + ((u >> 16) & 1u)) >> 16;   // RNE
  return (unsigned short)u;
}
__device__ __forceinline__ float bf2f(unsigned short h) {
  return __uint_as_float(((unsigned int)h) << 16);
}

__global__ void cast_f32_bf16(const float* __restrict__ in, unsigned short* __restrict__ out, int n) {
  int i = blockIdx.x * 256 + threadIdx.x;
  if (i < n) out[i] = f2bf(in[i]);
}

// ---------------- big GEMM (unchanged, verified in R1/R3) ----------------
template<int APERM, int CPERM, typename CT>
__global__ __launch_bounds__(256)
void gemm_bf16(const unsigned short* __restrict__ A, const unsigned short* __restrict__ W,
               const float* __restrict__ bias, CT* __restrict__ C, int M, int N, int K) {
  __shared__ __align__(16) unsigned short As[128 * 40];
  __shared__ __align__(16) unsigned short Ws[128 * 40];
  const int tid   = threadIdx.x;
  const int mBase = blockIdx.y * 128;
  const int nBase = blockIdx.x * 128;
  const int lane  = tid & 63;
  const int w     = tid >> 6;
  const int wm    = (w & 1) * 64;
  const int wn    = (w >> 1) * 64;
  const int r16   = lane & 15;
  const int q     = lane >> 4;

  f32x4 acc[4][4];
  for (int i = 0; i < 4; ++i)
    for (int j = 0; j < 4; ++j)
      for (int t = 0; t < 4; ++t) acc[i][j][t] = 0.f;

  const int r0  = tid >> 2;
  const int kk0 = (tid & 3) * 8;

  for (int k0 = 0; k0 < K; k0 += 32) {
    {
      int r = r0;
      size_t ar = APERM ? ((size_t)((mBase + r) & 31) * S_ + (size_t)((mBase + r) >> 5)) : (size_t)(mBase + r);
      *(uint4*)&As[r * 40 + kk0] = *(const uint4*)(A + ar * K + k0 + kk0);
      int r2 = r + 64;
      size_t ar2 = APERM ? ((size_t)((mBase + r2) & 31) * S_ + (size_t)((mBase + r2) >> 5)) : (size_t)(mBase + r2);
      *(uint4*)&As[r2 * 40 + kk0] = *(const uint4*)(A + ar2 * K + k0 + kk0);
      *(uint4*)&Ws[r * 40 + kk0]  = *(const uint4*)(W + (size_t)(nBase + r)  * K + k0 + kk0);
      *(uint4*)&Ws[r2 * 40 + kk0] = *(const uint4*)(W + (size_t)(nBase + r2) * K + k0 + kk0);
    }
    __syncthreads();
    bf16x8 af[4], bfr[4];
#pragma unroll
    for (int i = 0; i < 4; ++i) af[i]  = *(const bf16x8*)&As[(wm + i * 16 + r16) * 40 + q * 8];
#pragma unroll
    for (int j = 0; j < 4; ++j) bfr[j] = *(const bf16x8*)&Ws[(wn + j * 16 + r16) * 40 + q * 8];
#pragma unroll
    for (int i = 0; i < 4; ++i)
#pragma unroll
      for (int j = 0; j < 4; ++j)
        acc[i][j] = __builtin_amdgcn_mfma_f32_16x16x32_bf16(af[i], bfr[j], acc[i][j], 0, 0, 0);
    __syncthreads();
  }

#pragma unroll
  for (int i = 0; i < 4; ++i)
#pragma unroll
    for (int j = 0; j < 4; ++j)
#pragma unroll
      for (int t = 0; t < 4; ++t) {
        int m = mBase + wm + i * 16 + q * 4 + t;
        int n = nBase + wn + j * 16 + r16;
        float v = acc[i][j][t] + bias[n];
        size_t crow = CPERM ? ((size_t)(m & 31) * S_ + (size_t)(m >> 5)) : (size_t)m;
        if constexpr (sizeof(CT) == 4) C[crow * N + n] = v;
        else                           C[crow * N + n] = f2bf(v);
      }
}

// ---------------- persistent GRU layer, atomics-only coherence ----------------
// 64 blocks x 256 threads (4 waves). Block owns j-slice [j0,j0+16) of all 3 gates.
// Wave w: K-slice [w*256,(w+1)*256). Whh B-frags in registers (loaded once).
// h communicated via agent-scope relaxed atomics (compiler-legalized past L2).
// __syncthreads() after stores drains vmcnt -> stores at coherence point before
// the counter increment. No bulk cache fences; no inline asm.

template<typename XPT>
__global__ __launch_bounds__(256)
void gru_layer(const unsigned short* __restrict__ Whh, const XPT* __restrict__ xp,
               const unsigned short* __restrict__ h0b,
               unsigned short* __restrict__ y, float* __restrict__ hlast,
               unsigned int* __restrict__ ctrs) {
  __shared__ __align__(16) float part[4 * 6 * 64 * 4];   // 24 KB: [w][tile(m,g)][lane][reg]
  const int tid  = threadIdx.x;
  const int lane = tid & 63;
  const int w    = tid >> 6;          // K-slice id
  const int r16  = lane & 15;
  const int q    = lane >> 4;
  const int j0   = blockIdx.x * 16;

  // Whh B-frags -> registers (once). bw[g][c]: lane(r16,q) holds W[g*H+j0+r16][w*256+c*32+q*8..+8]
  bf16x8 bw[3][8];
#pragma unroll
  for (int g = 0; g < 3; ++g)
#pragma unroll
    for (int c = 0; c < 8; ++c)
      bw[g][c] = *(const bf16x8*)(Whh + (size_t)(g * H_ + j0 + r16) * H_ + w * 256 + c * 32 + q * 8);

  // fp32 h state + xp prefetch regs; epilogue mapping: v in {0,1}, e in {0,1}:
  //   o2 = v*128+tid, b = o2>>3, j = (o2&7)*2 + e
  float phv[4] = {0.f, 0.f, 0.f, 0.f};
  float pxr[4], pxz[4], pxn[4];
  if (tid < 128) {
#pragma unroll
    for (int v = 0; v < 2; ++v) {
      int o2 = v * 128 + tid, b = o2 >> 3, j = (o2 & 7) * 2;
#pragma unroll
      for (int e = 0; e < 2; ++e) {
        const XPT* x0 = xp + (size_t)b * G3_ + j0 + j + e;
        if constexpr (sizeof(XPT) == 4) {
          pxr[v * 2 + e] = x0[0]; pxz[v * 2 + e] = x0[H_]; pxn[v * 2 + e] = x0[2 * H_];
        } else {
          pxr[v * 2 + e] = bf2f(x0[0]); pxz[v * 2 + e] = bf2f(x0[H_]); pxn[v * 2 + e] = bf2f(x0[2 * H_]);
        }
      }
    }
  }

  for (int t = 0; t < S_; ++t) {
    if (t) {                          // wait for all blocks to finish step t-1
      if (w == 0) {
        unsigned tgt = (unsigned)t * 64u;
        int spins = 0;
        for (;;) {
          unsigned v = (lane < 8)
            ? __hip_atomic_load(&ctrs[lane * 16], __ATOMIC_RELAXED, __HIP_MEMORY_SCOPE_AGENT) : 0u;
          v += __shfl_xor(v, 1); v += __shfl_xor(v, 2); v += __shfl_xor(v, 4);
          v = __shfl(v, 0);
          if (v >= tgt) break;
          if (++spins > 32768) break;     // escape hatch: wrong answer beats a hang
          __builtin_amdgcn_s_sleep(1);
        }
      }
      __syncthreads();
      __atomic_signal_fence(__ATOMIC_SEQ_CST);
    }
    const unsigned short* hp = t ? y + (size_t)(t - 1) * (B_ * H_) : h0b;

    // A-frags via agent-scope u64 atomic loads (always fresh at coherence point)
    union AU { unsigned long long qq[2]; bf16x8 v; };
    AU a0[8], a1[8];
    {
      unsigned long long* pa0 = (unsigned long long*)(hp + (size_t)r16 * H_ + w * 256 + q * 8);
      unsigned long long* pa1 = (unsigned long long*)(hp + (size_t)(16 + r16) * H_ + w * 256 + q * 8);
#pragma unroll
      for (int c = 0; c < 8; ++c) {
        a0[c].qq[0] = __hip_atomic_load(pa0 + c * 8,     __ATOMIC_RELAXED, __HIP_MEMORY_SCOPE_AGENT);
        a0[c].qq[1] = __hip_atomic_load(pa0 + c * 8 + 1, __ATOMIC_RELAXED, __HIP_MEMORY_SCOPE_AGENT);
        a1[c].qq[0] = __hip_atomic_load(pa1 + c * 8,     __ATOMIC_RELAXED, __HIP_MEMORY_SCOPE_AGENT);
        a1[c].qq[1] = __hip_atomic_load(pa1 + c * 8 + 1, __ATOMIC_RELAXED, __HIP_MEMORY_SCOPE_AGENT);
      }
    }

    f32x4 acc[2][3];
#pragma unroll
    for (int m = 0; m < 2; ++m)
#pragma unroll
      for (int g = 0; g < 3; ++g)
#pragma unroll
        for (int u = 0; u < 4; ++u) acc[m][g][u] = 0.f;

#pragma unroll
    for (int c = 0; c < 8; ++c)
#pragma unroll
      for (int g = 0; g < 3; ++g) {
        acc[0][g] = __builtin_amdgcn_mfma_f32_16x16x32_bf16(a0[c].v, bw[g][c], acc[0][g], 0, 0, 0);
        acc[1][g] = __builtin_amdgcn_mfma_f32_16x16x32_bf16(a1[c].v, bw[g][c], acc[1][g], 0, 0, 0);
      }

#pragma unroll
    for (int m = 0; m < 2; ++m)
#pragma unroll
      for (int g = 0; g < 3; ++g)
        *(f32x4*)&part[((w * 6 + m * 3 + g) * 64 + lane) * 4] = acc[m][g];
    __syncthreads();

    if (tid < 128) {
      unsigned short* yt = y + (size_t)t * (B_ * H_);
#pragma unroll
      for (int v = 0; v < 2; ++v) {
        int o2 = v * 128 + tid, b = o2 >> 3, j = (o2 & 7) * 2;
        int m = b >> 4, q2 = (b >> 2) & 3, reg = b & 3;
        float hv2[2];
#pragma unroll
        for (int e = 0; e < 2; ++e) {
          int jj = j + e;
          float hr = 0.f, hz = 0.f, hn = 0.f;
#pragma unroll
          for (int ww = 0; ww < 4; ++ww) {
            int baseT = ww * 6 + m * 3;
            hr += part[((baseT + 0) * 64 + q2 * 16 + jj) * 4 + reg];
            hz += part[((baseT + 1) * 64 + q2 * 16 + jj) * 4 + reg];
            hn += part[((baseT + 2) * 64 + q2 * 16 + jj) * 4 + reg];
          }
          int pi = v * 2 + e;
          float r  = 1.f / (1.f + expf(-(pxr[pi] + hr)));
          float z  = 1.f / (1.f + expf(-(pxz[pi] + hz)));
          float nn = tanhf(pxn[pi] + hn + r * hn);
          float hv = (1.f - z) * nn + z * phv[pi];
          phv[pi] = hv;
          hv2[e] = hv;
        }
        unsigned int pk = (unsigned int)f2bf(hv2[0]) | ((unsigned int)f2bf(hv2[1]) << 16);
        __hip_atomic_store((unsigned int*)(yt + (size_t)b * H_ + j0 + j), pk,
                           __ATOMIC_RELAXED, __HIP_MEMORY_SCOPE_AGENT);
        if (t == S_ - 1) {
          hlast[b * H_ + j0 + j]     = hv2[0];
          hlast[b * H_ + j0 + j + 1] = hv2[1];
        }
      }
    }
    __atomic_signal_fence(__ATOMIC_SEQ_CST);
    __syncthreads();                 // drains each wave's vmcnt -> y stores at coherence point
    if (tid == 0)
      __hip_atomic_fetch_add(&ctrs[(blockIdx.x & 7) * 16], 1u,
                             __ATOMIC_RELAXED, __HIP_MEMORY_SCOPE_AGENT);
    if (tid < 128 && t + 1 < S_) {   // prefetch next step's xp (launch-constant), overlaps poll
      const XPT* xn = xp + (size_t)(t + 1) * (B_ * G3_);
#pragma unroll
      for (int v = 0; v < 2; ++v) {
        int o2 = v * 128 + tid, b = o2 >> 3, j = (o2 & 7) * 2;
#pragma unroll
        for (int e = 0; e < 2; ++e) {
          const XPT* x0 = xn + (size_t)b * G3_ + j0 + j + e;
          if constexpr (sizeof(XPT) == 4) {
            pxr[v * 2 + e] = x0[0]; pxz[v * 2 + e] = x0[H_]; pxn[v * 2 + e] = x0[2 * H_];
          } else {
            pxr[v * 2 + e] = bf2f(x0[0]); pxz[v * 2 + e] = bf2f(x0[H_]); pxn[v * 2 + e] = bf2f(x0[2 * H_]);
          }
        }
      }
    }
  }
}

extern "C" void kernel_launch(void* const* d_in, const int* in_sizes, int n_in,
                              void* d_out, int out_size, void* d_ws, size_t ws_size,
                              hipStream_t stream) {
  const float* x    = (const float*)d_in[0];
  const float* Wih0 = (const float*)d_in[1];
  const float* Whh0 = (const float*)d_in[2];
  const float* b0   = (const float*)d_in[3];
  const float* Wih1 = (const float*)d_in[4];
  const float* Whh1 = (const float*)d_in[5];
  const float* b1   = (const float*)d_in[6];
  const float* Wlin = (const float*)d_in[7];
  const float* blin = (const float*)d_in[8];
  float* out = (float*)d_out;

  const bool xpf32 = ws_size >= (size_t)308741120;
  char* p = (char*)d_ws;
  size_t off = 0;
  auto alloc = [&](size_t bytes) { void* r = p + off; off += (bytes + 255) & ~(size_t)255; return r; };

  void* xp = alloc(xpf32 ? (size_t)16384 * G3_ * 4 : (size_t)16384 * G3_ * 2);
  unsigned short* xb    = (unsigned short*)alloc((size_t)8388608 * 2);
  unsigned short* wih0b = (unsigned short*)alloc((size_t)1572864 * 2);
  unsigned short* whh0b = (unsigned short*)alloc((size_t)3145728 * 2);
  unsigned short* wih1b = (unsigned short*)alloc((size_t)3145728 * 2);
  unsigned short* whh1b = (unsigned short*)alloc((size_t)3145728 * 2);
  unsigned short* wlinb = (unsigned short*)alloc((size_t)524288 * 2);
  unsigned short* y0b   = (unsigned short*)alloc((size_t)16777216 * 2);  // (S,B,H) bf16
  unsigned short* y1b   = (unsigned short*)alloc((size_t)16777216 * 2);
  unsigned short* zerosB= (unsigned short*)alloc((size_t)B_ * H_ * 2);
  unsigned int* ctrs0   = (unsigned int*)alloc(512);
  unsigned int* ctrs1   = (unsigned int*)alloc(512);

  (void)hipMemsetAsync(zerosB, 0, (size_t)B_ * H_ * 2, stream);
  (void)hipMemsetAsync(ctrs0, 0, 512, stream);
  (void)hipMemsetAsync(ctrs1, 0, 512, stream);

  auto cast = [&](const float* in, unsigned short* o, int n) {
    cast_f32_bf16<<<n / 256, 256, 0, stream>>>(in, o, n);
  };
  cast(x, xb, 8388608);
  cast(Wih0, wih0b, 1572864);
  cast(Whh0, whh0b, 3145728);
  cast(Wih1, wih1b, 3145728);
  cast(Whh1, whh1b, 3145728);
  cast(Wlin, wlinb, 524288);

  float* hlast0 = out + 8388608;
  float* hlast1 = out + 8388608 + B_ * H_;

  // xproj0: (16384 x 3072 x 512), A = x batch-major (perm), C time-major
  {
    dim3 g(G3_ / 128, 16384 / 128);
    if (xpf32) gemm_bf16<1, 0, float><<<g, 256, 0, stream>>>(xb, wih0b, b0, (float*)xp, 16384, G3_, 512);
    else       gemm_bf16<1, 0, unsigned short><<<g, 256, 0, stream>>>(xb, wih0b, b0, (unsigned short*)xp, 16384, G3_, 512);
  }

  if (xpf32) gru_layer<float><<<64, 256, 0, stream>>>(whh0b, (const float*)xp, zerosB, y0b, hlast0, ctrs0);
  else       gru_layer<unsigned short><<<64, 256, 0, stream>>>(whh0b, (const unsigned short*)xp, zerosB, y0b, hlast0, ctrs0);

  // xproj1: (16384 x 3072 x 1024), A = y0b time-major
  {
    dim3 g(G3_ / 128, 16384 / 128);
    if (xpf32) gemm_bf16<0, 0, float><<<g, 256, 0, stream>>>(y0b, wih1b, b1, (float*)xp, 16384, G3_, 1024);
    else       gemm_bf16<0, 0, unsigned short><<<g, 256, 0, stream>>>(y0b, wih1b, b1, (unsigned short*)xp, 16384, G3_, 1024);
  }

  if (xpf32) gru_layer<float><<<64, 256, 0, stream>>>(whh1b, (const float*)xp, zerosB, y1b, hlast1, ctrs1);
  else       gru_layer<unsigned short><<<64, 256, 0, stream>>>(whh1b, (const unsigned short*)xp, zerosB, y1b, hlast1, ctrs1);

  // final: out = y1 @ Wlin^T + blin, C rows -> (b,s)
  {
    dim3 g(512 / 128, 16384 / 128);
    gemm_bf16<0, 1, float><<<g, 256, 0, stream>>>(y1b, wlinb, blin, out, 16384, 512, 1024);
  }
}